// Round 25
// baseline (213.306 us; speedup 1.0000x reference)
//
#include <hip/hip_runtime.h>
#include <hip/hip_bf16.h>
#include <hip/hip_fp16.h>
#include <math.h>

#define NN 100000
#define NE 1600000
#define SLOPE 0.2f
#define BSH 9                       // bucket = dst >> 9 (512 nodes/bucket)
#define NB 196                      // ceil(NN / 512)
#define BCAP 10240                  // records per bucket region (mean 8192)
#define CLDS 10752                  // LDS sort capacity (BCAP + 512 even-padding)
#define EPB 4096                    // edges per partition block
#define NTB 64                      // nodes per node_transform block

typedef float  f32x4 __attribute__((ext_vector_type(4)));
typedef unsigned int u32x4 __attribute__((ext_vector_type(4)));
typedef _Float16 half8 __attribute__((ext_vector_type(8)));
typedef float floatx4 __attribute__((ext_vector_type(4)));

// ---------------------------------------------------------------------------
// v[h*16+k] = sum_d attn[h,32+d] * W_edge[h*16+d, k]   (8x16 folded matrix)
// ---------------------------------------------------------------------------
__global__ __launch_bounds__(128) void prep_v_kernel(
    const float* __restrict__ W_edge, const float* __restrict__ attn,
    float* __restrict__ v)
{
    int t = threadIdx.x;            // t = h*16 + k
    int h = t >> 4, k = t & 15;
    float acc = 0.f;
#pragma unroll
    for (int d = 0; d < 16; ++d)
        acc += attn[h * 48 + 32 + d] * W_edge[(h * 16 + d) * 16 + k];
    v[t] = acc;
}

// ---------------------------------------------------------------------------
// MFMA node transform (r24-exact): h fp16; s_src/s_dst packed fp16x8.
// ---------------------------------------------------------------------------
__global__ __launch_bounds__(256) void node_transform(
    const float* __restrict__ X, const float* __restrict__ Wn,
    const float* __restrict__ attn, __half* __restrict__ h_fp,
    __half* __restrict__ s_src16, __half* __restrict__ s_dst16)
{
    __shared__ _Float16 Wl[128 * 128];          // 32 KB, swizzled

    int t = threadIdx.x;
#pragma unroll
    for (int it = 0; it < 8; ++it) {
        int gid = t + it * 256;
        int j  = gid >> 4;
        int gk = gid & 15;
        const float4* wp = reinterpret_cast<const float4*>(Wn + (size_t)j * 128 + gk * 8);
        float4 w0 = wp[0], w1 = wp[1];
        half8 hw;
        hw[0] = (_Float16)w0.x; hw[1] = (_Float16)w0.y;
        hw[2] = (_Float16)w0.z; hw[3] = (_Float16)w0.w;
        hw[4] = (_Float16)w1.x; hw[5] = (_Float16)w1.y;
        hw[6] = (_Float16)w1.z; hw[7] = (_Float16)w1.w;
        int sg = gk ^ (j & 7);
        *reinterpret_cast<half8*>(&Wl[j * 128 + sg * 8]) = hw;
    }
    __syncthreads();

    int lane = t & 63;
    int wave = t >> 6;
    int c = lane & 15;              // col within tile (j low bits / head dim d)
    int g = lane >> 4;              // k-group
    int n0 = blockIdx.x * NTB + wave * 16;
    if (n0 >= NN) return;

    floatx4 acc[8];
#pragma unroll
    for (int jt = 0; jt < 8; ++jt) acc[jt] = (floatx4){0.f, 0.f, 0.f, 0.f};

    const float4* xrow = reinterpret_cast<const float4*>(X + (size_t)(n0 + c) * 128);
#pragma unroll
    for (int kb = 0; kb < 4; ++kb) {
        float4 x0 = xrow[kb * 8 + g * 2];
        float4 x1 = xrow[kb * 8 + g * 2 + 1];
        half8 a;
        a[0] = (_Float16)x0.x; a[1] = (_Float16)x0.y;
        a[2] = (_Float16)x0.z; a[3] = (_Float16)x0.w;
        a[4] = (_Float16)x1.x; a[5] = (_Float16)x1.y;
        a[6] = (_Float16)x1.z; a[7] = (_Float16)x1.w;
#pragma unroll
        for (int jt = 0; jt < 8; ++jt) {
            int sg = (kb * 4 + g) ^ (c & 7);
            half8 b = *reinterpret_cast<const half8*>(&Wl[(jt * 16 + c) * 128 + sg * 8]);
            acc[jt] = __builtin_amdgcn_mfma_f32_16x16x32_f16(a, b, acc[jt], 0, 0, 0);
        }
    }

    float as_l[8], ad_l[8];
#pragma unroll
    for (int jt = 0; jt < 8; ++jt) {
        as_l[jt] = attn[jt * 48 + c];
        ad_l[jt] = attn[jt * 48 + 16 + c];
    }

#pragma unroll
    for (int r = 0; r < 4; ++r) {
        int node = n0 + g * 4 + r;
        unsigned int ps16[8], pd16[8];
#pragma unroll
        for (int jt = 0; jt < 8; ++jt) {
            float hv = acc[jt][r];
            h_fp[(size_t)node * 128 + jt * 16 + c] = __float2half_rn(hv);
            float p1 = hv * as_l[jt];
            float p2 = hv * ad_l[jt];
#pragma unroll
            for (int m = 1; m < 16; m <<= 1) {
                p1 += __shfl_xor(p1, m);
                p2 += __shfl_xor(p2, m);
            }
            ps16[jt] = (unsigned int)__half_as_ushort(__float2half_rn(p1));
            pd16[jt] = (unsigned int)__half_as_ushort(__float2half_rn(p2));
        }
        if (c == 0) {
            u32x4 vs, vd;
            vs[0] = ps16[0] | (ps16[1] << 16);
            vs[1] = ps16[2] | (ps16[3] << 16);
            vs[2] = ps16[4] | (ps16[5] << 16);
            vs[3] = ps16[6] | (ps16[7] << 16);
            vd[0] = pd16[0] | (pd16[1] << 16);
            vd[1] = pd16[2] | (pd16[3] << 16);
            vd[2] = pd16[4] | (pd16[5] << 16);
            vd[3] = pd16[6] | (pd16[7] << 16);
            *reinterpret_cast<u32x4*>(&s_src16[(size_t)node * 8]) = vs;
            *reinterpret_cast<u32x4*>(&s_dst16[(size_t)node * 8]) = vd;
        }
    }
}

// ---------------------------------------------------------------------------
// FUSED score + partition (r24 phase-1 with fp16 s) + r17 esc-slab writeout:
// phase 1 stores esc4[e] NORMALLY (stays L2-hot in this block's 64KB
// window); phase 4 re-reads esc4[e] (L2 hit) and writes esc_s[b*BCAP+gpos]
// coalesced next to the record. Record key = (gpos<<9)|lowdst (bucket-local
// esc index, opaque to the sort).
// ---------------------------------------------------------------------------
__global__ __launch_bounds__(256) void edge_score_partition(
    const int* __restrict__ ei, const float* __restrict__ ef,
    const float* __restrict__ vglob, const __half* __restrict__ s_src16,
    const __half* __restrict__ s_dst16, unsigned int* __restrict__ bcursor,
    u32x4* __restrict__ esc4, u32x4* __restrict__ esc_s,
    int2* __restrict__ brec)
{
    __shared__ float v[128];
    __shared__ unsigned int hist[256];
    __shared__ unsigned int runstart[256];
    __shared__ unsigned int cursor[256];
    __shared__ unsigned int gbase[NB];
    __shared__ int           sdst[EPB];
    __shared__ int           ssin[EPB];
    __shared__ unsigned int  skey[EPB];
    __shared__ unsigned int  ssrc[EPB];
    __shared__ unsigned short sbkt[EPB];

    int t = threadIdx.x;
    int e0 = blockIdx.x * EPB;
    int ecnt = min(EPB, NE - e0);

    if (t < 128) v[t] = vglob[t];
    hist[t] = 0;
    __syncthreads();

    const f32x4* ef4 = reinterpret_cast<const f32x4*>(ef);

    for (int i = t; i < ecnt; i += 256) {
        int e = e0 + i;
        int src = ei[e];
        int dst = ei[NE + e];
        sdst[i] = dst;
        ssin[i] = src;
        atomicAdd(&hist[dst >> BSH], 1u);

        float tt[8] = {0.f, 0.f, 0.f, 0.f, 0.f, 0.f, 0.f, 0.f};
#pragma unroll
        for (int r = 0; r < 4; ++r) {
            f32x4 fv = ef4[(size_t)e * 4 + r];
#pragma unroll
            for (int hh = 0; hh < 8; ++hh) {
                tt[hh] += fv[0] * v[hh * 16 + r * 4 + 0]
                        + fv[1] * v[hh * 16 + r * 4 + 1]
                        + fv[2] * v[hh * 16 + r * 4 + 2]
                        + fv[3] * v[hh * 16 + r * 4 + 3];
            }
        }
        u32x4 us = *reinterpret_cast<const u32x4*>(&s_src16[(size_t)src * 8]);
        u32x4 ud = *reinterpret_cast<const u32x4*>(&s_dst16[(size_t)dst * 8]);
        float sa[8], sb[8];
#pragma unroll
        for (int p = 0; p < 4; ++p) {
            unsigned int uw0 = us[p];
            unsigned int uw1 = ud[p];
            float2 fs = __half22float2(*reinterpret_cast<const __half2*>(&uw0));
            float2 fd = __half22float2(*reinterpret_cast<const __half2*>(&uw1));
            sa[p * 2] = fs.x; sa[p * 2 + 1] = fs.y;
            sb[p * 2] = fd.x; sb[p * 2 + 1] = fd.y;
        }
        u32x4 pk4;
#pragma unroll
        for (int hp = 0; hp < 4; ++hp) {
            unsigned int lohi[2];
#pragma unroll
            for (int half_ = 0; half_ < 2; ++half_) {
                int hh = hp * 2 + half_;
                float s = sa[hh] + sb[hh] + tt[hh];
                s = (s >= 0.f) ? s : SLOPE * s;
                lohi[half_] = (unsigned int)__half_as_ushort(__float2half_rn(__expf(s)));
            }
            pk4[hp] = lohi[0] | (lohi[1] << 16);
        }
        esc4[e] = pk4;                 // NORMAL store: phase 4 re-reads from L2
    }
    __syncthreads();

    // exclusive scan of hist (256 entries, Hillis-Steele)
    unsigned int hv = hist[t];
    runstart[t] = hv;
    __syncthreads();
    for (int o = 1; o < 256; o <<= 1) {
        unsigned int u = (t >= o) ? runstart[t - o] : 0u;
        __syncthreads();
        runstart[t] += u;
        __syncthreads();
    }
    unsigned int excl = runstart[t] - hv;
    __syncthreads();
    runstart[t] = excl;
    cursor[t] = excl;
    if (t < NB) gbase[t] = atomicAdd(&bcursor[t], hv);
    __syncthreads();

    // reorder into LDS by bucket (all operands already in LDS)
    for (int i = t; i < ecnt; i += 256) {
        int e = e0 + i;
        int dst = sdst[i];
        int b = dst >> BSH;
        unsigned int slot = atomicAdd(&cursor[b], 1u);
        skey[slot] = ((unsigned int)e << BSH) | (unsigned int)(dst & 511);
        ssrc[slot] = (unsigned int)ssin[i];
        sbkt[slot] = (unsigned short)b;
    }
    __syncthreads();

    // coalesced writeout: record {(gpos<<9)|lowdst, src} + esc_s[gpos]=esc4[e]
    for (int s = t; s < ecnt; s += 256) {
        int b = sbkt[s];
        unsigned int gpos = gbase[b] + ((unsigned int)s - runstart[b]);
        if (gpos < BCAP) {
            unsigned int key = skey[s];
            unsigned int e = key >> BSH;
            brec[(size_t)b * BCAP + gpos] =
                make_int2((int)((gpos << BSH) | (key & 511u)), (int)ssrc[s]);
            esc_s[(size_t)b * BCAP + gpos] = esc4[e];   // L2-hot gather, coalesced write
        }
    }
}

// ---------------------------------------------------------------------------
// Bucket sort (r15/r24 form): key's high bits (bucket-local esc index) are
// opaque. Sorts records by node, writes back fully linear. noff[n]={off,cnt}.
// ---------------------------------------------------------------------------
__global__ __launch_bounds__(512) void bucket_sort(
    const unsigned int* __restrict__ bcursor, int2* __restrict__ brec,
    uint2* __restrict__ noff)
{
    __shared__ unsigned int ncnt[512];
    __shared__ unsigned int offL[513];
    __shared__ unsigned int ncur[512];
    __shared__ unsigned int se[CLDS];
    __shared__ unsigned int ss[CLDS];

    int t = threadIdx.x;
    int b = blockIdx.x;
    int n0 = b << BSH;
    unsigned int cnt = bcursor[b];
    if (cnt > BCAP) cnt = BCAP;
    int2* rin = brec + (size_t)b * BCAP;

    ncnt[t] = 0;
    __syncthreads();
    for (unsigned int i = t; i < cnt; i += 512)
        atomicAdd(&ncnt[(unsigned int)rin[i].x & 511u], 1u);
    __syncthreads();
    unsigned int ec = (ncnt[t] + 1u) & ~1u;
    offL[t] = ec;
    __syncthreads();
    for (int o = 1; o < 512; o <<= 1) {
        unsigned int u = (t >= o) ? offL[t - o] : 0u;
        __syncthreads();
        offL[t] += u;
        __syncthreads();
    }
    unsigned int incl = offL[t];
    unsigned int excl = incl - ec;
    __syncthreads();
    offL[t] = excl;
    ncur[t] = 0;
    if (t == 511) offL[512] = incl;
    __syncthreads();
    for (unsigned int i = t; i < cnt; i += 512) {
        int2 r = rin[i];
        unsigned int key = (unsigned int)r.x;
        unsigned int ld = key & 511u;
        unsigned int pos = atomicAdd(&ncur[ld], 1u);
        unsigned int slot = offL[ld] + pos;
        if (slot < CLDS) {
            se[slot] = key >> BSH;              // bucket-local esc index (gpos)
            ss[slot] = (unsigned int)r.y;       // src
        }
    }
    __syncthreads();
    unsigned int total = offL[512];
    if (total > BCAP) total = BCAP;
    for (unsigned int s = t; s < total; s += 512) {
        unsigned int g = se[s];
        if (g >= BCAP) g = 0;                   // gap-slot clamp (r19 lesson)
        rin[s] = make_int2((int)g, (int)ss[s]);
    }
    int n = n0 + t;
    if (n < NN)
        noff[n] = make_uint2((unsigned int)b * BCAP + offL[t], ncnt[t]);
}

// ---------------------------------------------------------------------------
// One wave per node, single pass, unroll x8 (+x4 +scalar tail).
// esc read from the CSR-slab esc_s via the record's bucket-local index:
// random only within the bucket's 160KB slab -> L2-resident per XCD.
// Lane owns dims {2*lane,2*lane+1}; head q = lane>>3.
// ---------------------------------------------------------------------------
__global__ __launch_bounds__(256) void node_aggregate(
    const uint2* __restrict__ noff, const int2* __restrict__ perm2,
    const __half* __restrict__ esc_s, const __half* __restrict__ h_fp,
    float* __restrict__ out)
{
    int lane = threadIdx.x & 63;
    int n = blockIdx.x * (blockDim.x >> 6) + (threadIdx.x >> 6);
    if (n >= NN) return;
    int q = lane >> 3;
    const unsigned int* hl = reinterpret_cast<const unsigned int*>(h_fp) + lane;
    const __half* el = esc_s + ((size_t)(n >> BSH) * BCAP) * 8 + q;

    uint2 oc = noff[n];
    unsigned int s0 = oc.x, s1 = s0 + oc.y;
    float denom = 0.f, a0 = 0.f, a1 = 0.f;
    unsigned int i = s0;

    for (; i + 8 <= s1; i += 8) {
        int4 pa = *reinterpret_cast<const int4*>(&perm2[i]);
        int4 pb = *reinterpret_cast<const int4*>(&perm2[i + 2]);
        int4 pc = *reinterpret_cast<const int4*>(&perm2[i + 4]);
        int4 pd = *reinterpret_cast<const int4*>(&perm2[i + 6]);
        unsigned int u0 = hl[(size_t)pa.y * 64];
        unsigned int u1 = hl[(size_t)pa.w * 64];
        unsigned int u2 = hl[(size_t)pb.y * 64];
        unsigned int u3 = hl[(size_t)pb.w * 64];
        unsigned int u4 = hl[(size_t)pc.y * 64];
        unsigned int u5 = hl[(size_t)pc.w * 64];
        unsigned int u6 = hl[(size_t)pd.y * 64];
        unsigned int u7 = hl[(size_t)pd.w * 64];
        float e0 = __half2float(el[(size_t)pa.x * 8]);
        float e1 = __half2float(el[(size_t)pa.z * 8]);
        float e2 = __half2float(el[(size_t)pb.x * 8]);
        float e3 = __half2float(el[(size_t)pb.z * 8]);
        float e4 = __half2float(el[(size_t)pc.x * 8]);
        float e5 = __half2float(el[(size_t)pc.z * 8]);
        float e6 = __half2float(el[(size_t)pd.x * 8]);
        float e7 = __half2float(el[(size_t)pd.z * 8]);
        float2 h0 = __half22float2(*reinterpret_cast<const __half2*>(&u0));
        float2 h1 = __half22float2(*reinterpret_cast<const __half2*>(&u1));
        float2 h2 = __half22float2(*reinterpret_cast<const __half2*>(&u2));
        float2 h3 = __half22float2(*reinterpret_cast<const __half2*>(&u3));
        float2 h4 = __half22float2(*reinterpret_cast<const __half2*>(&u4));
        float2 h5 = __half22float2(*reinterpret_cast<const __half2*>(&u5));
        float2 h6 = __half22float2(*reinterpret_cast<const __half2*>(&u6));
        float2 h7 = __half22float2(*reinterpret_cast<const __half2*>(&u7));
        denom += ((e0 + e1) + (e2 + e3)) + ((e4 + e5) + (e6 + e7));
        a0 = fmaf(h0.x, e0, a0); a0 = fmaf(h1.x, e1, a0);
        a0 = fmaf(h2.x, e2, a0); a0 = fmaf(h3.x, e3, a0);
        a0 = fmaf(h4.x, e4, a0); a0 = fmaf(h5.x, e5, a0);
        a0 = fmaf(h6.x, e6, a0); a0 = fmaf(h7.x, e7, a0);
        a1 = fmaf(h0.y, e0, a1); a1 = fmaf(h1.y, e1, a1);
        a1 = fmaf(h2.y, e2, a1); a1 = fmaf(h3.y, e3, a1);
        a1 = fmaf(h4.y, e4, a1); a1 = fmaf(h5.y, e5, a1);
        a1 = fmaf(h6.y, e6, a1); a1 = fmaf(h7.y, e7, a1);
    }
    for (; i + 4 <= s1; i += 4) {
        int4 pa = *reinterpret_cast<const int4*>(&perm2[i]);
        int4 pb = *reinterpret_cast<const int4*>(&perm2[i + 2]);
        unsigned int u0 = hl[(size_t)pa.y * 64];
        unsigned int u1 = hl[(size_t)pa.w * 64];
        unsigned int u2 = hl[(size_t)pb.y * 64];
        unsigned int u3 = hl[(size_t)pb.w * 64];
        float e0 = __half2float(el[(size_t)pa.x * 8]);
        float e1 = __half2float(el[(size_t)pa.z * 8]);
        float e2 = __half2float(el[(size_t)pb.x * 8]);
        float e3 = __half2float(el[(size_t)pb.z * 8]);
        float2 h0 = __half22float2(*reinterpret_cast<const __half2*>(&u0));
        float2 h1 = __half22float2(*reinterpret_cast<const __half2*>(&u1));
        float2 h2 = __half22float2(*reinterpret_cast<const __half2*>(&u2));
        float2 h3 = __half22float2(*reinterpret_cast<const __half2*>(&u3));
        denom += (e0 + e1) + (e2 + e3);
        a0 = fmaf(h0.x, e0, a0); a0 = fmaf(h1.x, e1, a0);
        a0 = fmaf(h2.x, e2, a0); a0 = fmaf(h3.x, e3, a0);
        a1 = fmaf(h0.y, e0, a1); a1 = fmaf(h1.y, e1, a1);
        a1 = fmaf(h2.y, e2, a1); a1 = fmaf(h3.y, e3, a1);
    }
    for (; i < s1; ++i) {
        int2 p = perm2[i];
        unsigned int u = hl[(size_t)p.y * 64];
        float e = __half2float(el[(size_t)p.x * 8]);
        float2 hf = __half22float2(*reinterpret_cast<const __half2*>(&u));
        denom += e;
        a0 = fmaf(hf.x, e, a0);
        a1 = fmaf(hf.y, e, a1);
    }

    float w = 1.f / (denom + 1e-9f);
    a0 *= w; a1 *= w;
    a0 = a0 > 0.f ? a0 : expm1f(a0);
    a1 = a1 > 0.f ? a1 : expm1f(a1);
    reinterpret_cast<float2*>(out)[(size_t)n * 64 + lane] = make_float2(a0, a1);
}

extern "C" void kernel_launch(void* const* d_in, const int* in_sizes, int n_in,
                              void* d_out, int out_size, void* d_ws, size_t ws_size,
                              hipStream_t stream)
{
    const float* X    = (const float*)d_in[0];   // (N,128)
    const float* EF   = (const float*)d_in[1];   // (E,16)
    const float* Wn   = (const float*)d_in[2];   // (128,128)
    const float* We   = (const float*)d_in[3];   // (128,16)
    const float* attn = (const float*)d_in[4];   // (8,48)
    const int*   ei   = (const int*)d_in[5];     // (2,E)
    float* out = (float*)d_out;                  // (N,128)

    char* ws = (char*)d_ws;
    int2*   brec   = (int2*)ws;                                  // NB*BCAP int2 = 16.1MB
    u32x4*  esc4   = (u32x4*)(brec + (size_t)NB * BCAP);         // NE x 16B (edge order)
    u32x4*  esc_s  = esc4 + NE;                                  // NB*BCAP x 16B (slab)
    __half* s_src16 = (__half*)(esc_s + (size_t)NB * BCAP);      // NN*8 fp16
    __half* s_dst16 = s_src16 + (size_t)NN * 8;                  // NN*8 fp16
    float*  vbuf   = (float*)(s_dst16 + (size_t)NN * 8);         // 128
    unsigned int* bcursor = (unsigned int*)(vbuf + 128);         // 256
    uint2*  noff   = (uint2*)(bcursor + 256);                    // NN uint2
    __half* h_fp   = (__half*)(noff + NN);                       // NN*128 fp16

    hipMemsetAsync(bcursor, 0, 256 * sizeof(unsigned int), stream);

    prep_v_kernel<<<1, 128, 0, stream>>>(We, attn, vbuf);
    node_transform<<<(NN + NTB - 1) / NTB, 256, 0, stream>>>(X, Wn, attn, h_fp,
                                                             s_src16, s_dst16);
    edge_score_partition<<<(NE + EPB - 1) / EPB, 256, 0, stream>>>(
        ei, EF, vbuf, s_src16, s_dst16, bcursor, esc4, esc_s, brec);
    bucket_sort<<<NB, 512, 0, stream>>>(bcursor, brec, noff);
    node_aggregate<<<(NN + 3) / 4, 256, 0, stream>>>(noff, brec,
                                                     (const __half*)esc_s,
                                                     h_fp, out);
}

// Round 26
// 200.525 us; speedup vs baseline: 1.0637x; 1.0637x over previous
//
#include <hip/hip_runtime.h>
#include <hip/hip_bf16.h>
#include <hip/hip_fp16.h>
#include <math.h>

#define NN 100000
#define NE 1600000
#define SLOPE 0.2f
#define BSH 9                       // bucket = dst >> 9 (512 nodes/bucket)
#define NB 196                      // ceil(NN / 512)
#define BCAP 10240                  // records per bucket region (mean 8192)
#define CLDS 10752                  // LDS sort capacity (BCAP + 512 even-padding)
#define EPB 4096                    // edges per partition block
#define NTB 64                      // nodes per node_transform block

typedef float  f32x4 __attribute__((ext_vector_type(4)));
typedef unsigned int u32x4 __attribute__((ext_vector_type(4)));
typedef _Float16 half8 __attribute__((ext_vector_type(8)));
typedef float floatx4 __attribute__((ext_vector_type(4)));

// ---------------------------------------------------------------------------
// v[h*16+k] = sum_d attn[h,32+d] * W_edge[h*16+d, k]   (8x16 folded matrix)
// ---------------------------------------------------------------------------
__global__ __launch_bounds__(128) void prep_v_kernel(
    const float* __restrict__ W_edge, const float* __restrict__ attn,
    float* __restrict__ v)
{
    int t = threadIdx.x;            // t = h*16 + k
    int h = t >> 4, k = t & 15;
    float acc = 0.f;
#pragma unroll
    for (int d = 0; d < 16; ++d)
        acc += attn[h * 48 + 32 + d] * W_edge[(h * 16 + d) * 16 + k];
    v[t] = acc;
}

// ---------------------------------------------------------------------------
// MFMA node transform: h[n,j] = X[n,:] . Wn[j,:] via mfma_f32_16x16x32_f16.
// s_src/s_dst packed fp16x8 (16B/node) -> combined 3.2MB fits per-XCD L2
// for the edge pass's random gathers.
// ---------------------------------------------------------------------------
__global__ __launch_bounds__(256) void node_transform(
    const float* __restrict__ X, const float* __restrict__ Wn,
    const float* __restrict__ attn, __half* __restrict__ h_fp,
    __half* __restrict__ s_src16, __half* __restrict__ s_dst16)
{
    __shared__ _Float16 Wl[128 * 128];          // 32 KB, swizzled

    int t = threadIdx.x;
#pragma unroll
    for (int it = 0; it < 8; ++it) {
        int gid = t + it * 256;
        int j  = gid >> 4;
        int gk = gid & 15;
        const float4* wp = reinterpret_cast<const float4*>(Wn + (size_t)j * 128 + gk * 8);
        float4 w0 = wp[0], w1 = wp[1];
        half8 hw;
        hw[0] = (_Float16)w0.x; hw[1] = (_Float16)w0.y;
        hw[2] = (_Float16)w0.z; hw[3] = (_Float16)w0.w;
        hw[4] = (_Float16)w1.x; hw[5] = (_Float16)w1.y;
        hw[6] = (_Float16)w1.z; hw[7] = (_Float16)w1.w;
        int sg = gk ^ (j & 7);
        *reinterpret_cast<half8*>(&Wl[j * 128 + sg * 8]) = hw;
    }
    __syncthreads();

    int lane = t & 63;
    int wave = t >> 6;
    int c = lane & 15;              // col within tile (j low bits / head dim d)
    int g = lane >> 4;              // k-group
    int n0 = blockIdx.x * NTB + wave * 16;
    if (n0 >= NN) return;

    floatx4 acc[8];
#pragma unroll
    for (int jt = 0; jt < 8; ++jt) acc[jt] = (floatx4){0.f, 0.f, 0.f, 0.f};

    const float4* xrow = reinterpret_cast<const float4*>(X + (size_t)(n0 + c) * 128);
#pragma unroll
    for (int kb = 0; kb < 4; ++kb) {
        float4 x0 = xrow[kb * 8 + g * 2];
        float4 x1 = xrow[kb * 8 + g * 2 + 1];
        half8 a;
        a[0] = (_Float16)x0.x; a[1] = (_Float16)x0.y;
        a[2] = (_Float16)x0.z; a[3] = (_Float16)x0.w;
        a[4] = (_Float16)x1.x; a[5] = (_Float16)x1.y;
        a[6] = (_Float16)x1.z; a[7] = (_Float16)x1.w;
#pragma unroll
        for (int jt = 0; jt < 8; ++jt) {
            int sg = (kb * 4 + g) ^ (c & 7);
            half8 b = *reinterpret_cast<const half8*>(&Wl[(jt * 16 + c) * 128 + sg * 8]);
            acc[jt] = __builtin_amdgcn_mfma_f32_16x16x32_f16(a, b, acc[jt], 0, 0, 0);
        }
    }

    float as_l[8], ad_l[8];
#pragma unroll
    for (int jt = 0; jt < 8; ++jt) {
        as_l[jt] = attn[jt * 48 + c];
        ad_l[jt] = attn[jt * 48 + 16 + c];
    }

#pragma unroll
    for (int r = 0; r < 4; ++r) {
        int node = n0 + g * 4 + r;
        unsigned int ps16[8], pd16[8];
#pragma unroll
        for (int jt = 0; jt < 8; ++jt) {
            float hv = acc[jt][r];
            h_fp[(size_t)node * 128 + jt * 16 + c] = __float2half_rn(hv);
            float p1 = hv * as_l[jt];
            float p2 = hv * ad_l[jt];
#pragma unroll
            for (int m = 1; m < 16; m <<= 1) {
                p1 += __shfl_xor(p1, m);
                p2 += __shfl_xor(p2, m);
            }
            ps16[jt] = (unsigned int)__half_as_ushort(__float2half_rn(p1));
            pd16[jt] = (unsigned int)__half_as_ushort(__float2half_rn(p2));
        }
        if (c == 0) {
            u32x4 vs, vd;
            vs[0] = ps16[0] | (ps16[1] << 16);
            vs[1] = ps16[2] | (ps16[3] << 16);
            vs[2] = ps16[4] | (ps16[5] << 16);
            vs[3] = ps16[6] | (ps16[7] << 16);
            vd[0] = pd16[0] | (pd16[1] << 16);
            vd[1] = pd16[2] | (pd16[3] << 16);
            vd[2] = pd16[4] | (pd16[5] << 16);
            vd[3] = pd16[6] | (pd16[7] << 16);
            *reinterpret_cast<u32x4*>(&s_src16[(size_t)node * 8]) = vs;
            *reinterpret_cast<u32x4*>(&s_dst16[(size_t)node * 8]) = vd;
        }
    }
}

// ---------------------------------------------------------------------------
// FUSED score + partition (r15 structure): phase 1 scores all edges
// (lrelu+exp -> 8x fp16, LINEAR NT store at index e) while staging src/dst
// in LDS and histogramming buckets; scan; one atomicAdd/bucket/block; LDS
// reorder; coalesced region writeout of records {(e<<9)|lowdst, src}.
// s gathers are 16B fp16x8 from the 3.2MB L2-resident buffers.
// ---------------------------------------------------------------------------
__global__ __launch_bounds__(256) void edge_score_partition(
    const int* __restrict__ ei, const float* __restrict__ ef,
    const float* __restrict__ vglob, const __half* __restrict__ s_src16,
    const __half* __restrict__ s_dst16, unsigned int* __restrict__ bcursor,
    u32x4* __restrict__ esc4, int2* __restrict__ brec)
{
    __shared__ float v[128];
    __shared__ unsigned int hist[256];
    __shared__ unsigned int runstart[256];
    __shared__ unsigned int cursor[256];
    __shared__ unsigned int gbase[NB];
    __shared__ int           sdst[EPB];
    __shared__ int           ssin[EPB];
    __shared__ unsigned int  skey[EPB];
    __shared__ unsigned int  ssrc[EPB];
    __shared__ unsigned short sbkt[EPB];

    int t = threadIdx.x;
    int e0 = blockIdx.x * EPB;
    int ecnt = min(EPB, NE - e0);

    if (t < 128) v[t] = vglob[t];
    hist[t] = 0;
    __syncthreads();

    const f32x4* ef4 = reinterpret_cast<const f32x4*>(ef);

    for (int i = t; i < ecnt; i += 256) {
        int e = e0 + i;
        int src = ei[e];
        int dst = ei[NE + e];
        sdst[i] = dst;
        ssin[i] = src;
        atomicAdd(&hist[dst >> BSH], 1u);

        float tt[8] = {0.f, 0.f, 0.f, 0.f, 0.f, 0.f, 0.f, 0.f};
#pragma unroll
        for (int r = 0; r < 4; ++r) {
            f32x4 fv = ef4[(size_t)e * 4 + r];
#pragma unroll
            for (int hh = 0; hh < 8; ++hh) {
                tt[hh] += fv[0] * v[hh * 16 + r * 4 + 0]
                        + fv[1] * v[hh * 16 + r * 4 + 1]
                        + fv[2] * v[hh * 16 + r * 4 + 2]
                        + fv[3] * v[hh * 16 + r * 4 + 3];
            }
        }
        u32x4 us = *reinterpret_cast<const u32x4*>(&s_src16[(size_t)src * 8]);
        u32x4 ud = *reinterpret_cast<const u32x4*>(&s_dst16[(size_t)dst * 8]);
        float sa[8], sb[8];
#pragma unroll
        for (int p = 0; p < 4; ++p) {
            unsigned int uw0 = us[p];
            unsigned int uw1 = ud[p];
            float2 fs = __half22float2(*reinterpret_cast<const __half2*>(&uw0));
            float2 fd = __half22float2(*reinterpret_cast<const __half2*>(&uw1));
            sa[p * 2] = fs.x; sa[p * 2 + 1] = fs.y;
            sb[p * 2] = fd.x; sb[p * 2 + 1] = fd.y;
        }
        u32x4 pk4;
#pragma unroll
        for (int hp = 0; hp < 4; ++hp) {
            unsigned int lohi[2];
#pragma unroll
            for (int half_ = 0; half_ < 2; ++half_) {
                int hh = hp * 2 + half_;
                float s = sa[hh] + sb[hh] + tt[hh];
                s = (s >= 0.f) ? s : SLOPE * s;
                lohi[half_] = (unsigned int)__half_as_ushort(__float2half_rn(__expf(s)));
            }
            pk4[hp] = lohi[0] | (lohi[1] << 16);
        }
        __builtin_nontemporal_store(pk4, &esc4[e]);
    }
    __syncthreads();

    // exclusive scan of hist (256 entries, Hillis-Steele)
    unsigned int hv = hist[t];
    runstart[t] = hv;
    __syncthreads();
    for (int o = 1; o < 256; o <<= 1) {
        unsigned int u = (t >= o) ? runstart[t - o] : 0u;
        __syncthreads();
        runstart[t] += u;
        __syncthreads();
    }
    unsigned int excl = runstart[t] - hv;
    __syncthreads();
    runstart[t] = excl;
    cursor[t] = excl;
    if (t < NB) gbase[t] = atomicAdd(&bcursor[t], hv);
    __syncthreads();

    // reorder into LDS by bucket (all operands already in LDS)
    for (int i = t; i < ecnt; i += 256) {
        int e = e0 + i;
        int dst = sdst[i];
        int b = dst >> BSH;
        unsigned int slot = atomicAdd(&cursor[b], 1u);
        skey[slot] = ((unsigned int)e << BSH) | (unsigned int)(dst & 511);
        ssrc[slot] = (unsigned int)ssin[i];
        sbkt[slot] = (unsigned short)b;
    }
    __syncthreads();

    // coalesced writeout: consecutive slots -> consecutive region addresses
    for (int s = t; s < ecnt; s += 256) {
        int b = sbkt[s];
        unsigned int gpos = gbase[b] + ((unsigned int)s - runstart[b]);
        if (gpos < BCAP)
            brec[(size_t)b * BCAP + gpos] = make_int2((int)skey[s], (int)ssrc[s]);
    }
}

// ---------------------------------------------------------------------------
// Bucket sort (r15 form): one block per bucket. Count per-node (LDS
// atomics), scan even-padded counts (-> int4-aligned rows), scatter sorted
// into LDS, write back fully LINEAR. Records {e, src}. noff[n]={off,cnt}.
// ---------------------------------------------------------------------------
__global__ __launch_bounds__(512) void bucket_sort(
    const unsigned int* __restrict__ bcursor, int2* __restrict__ brec,
    uint2* __restrict__ noff)
{
    __shared__ unsigned int ncnt[512];
    __shared__ unsigned int offL[513];
    __shared__ unsigned int ncur[512];
    __shared__ unsigned int se[CLDS];
    __shared__ unsigned int ss[CLDS];

    int t = threadIdx.x;
    int b = blockIdx.x;
    int n0 = b << BSH;
    unsigned int cnt = bcursor[b];
    if (cnt > BCAP) cnt = BCAP;
    int2* rin = brec + (size_t)b * BCAP;

    ncnt[t] = 0;
    __syncthreads();
    for (unsigned int i = t; i < cnt; i += 512)
        atomicAdd(&ncnt[(unsigned int)rin[i].x & 511u], 1u);
    __syncthreads();
    unsigned int ec = (ncnt[t] + 1u) & ~1u;
    offL[t] = ec;
    __syncthreads();
    for (int o = 1; o < 512; o <<= 1) {
        unsigned int u = (t >= o) ? offL[t - o] : 0u;
        __syncthreads();
        offL[t] += u;
        __syncthreads();
    }
    unsigned int incl = offL[t];
    unsigned int excl = incl - ec;
    __syncthreads();
    offL[t] = excl;
    ncur[t] = 0;
    if (t == 511) offL[512] = incl;
    __syncthreads();
    for (unsigned int i = t; i < cnt; i += 512) {
        int2 r = rin[i];
        unsigned int key = (unsigned int)r.x;
        unsigned int ld = key & 511u;
        unsigned int pos = atomicAdd(&ncur[ld], 1u);
        unsigned int slot = offL[ld] + pos;
        if (slot < CLDS) {
            se[slot] = key >> BSH;              // e
            ss[slot] = (unsigned int)r.y;       // src
        }
    }
    __syncthreads();
    unsigned int total = offL[512];
    if (total > BCAP) total = BCAP;
    for (unsigned int s = t; s < total; s += 512)
        rin[s] = make_int2((int)se[s], (int)ss[s]);
    int n = n0 + t;
    if (n < NN)
        noff[n] = make_uint2((unsigned int)b * BCAP + offL[t], ncnt[t]);
}

// ---------------------------------------------------------------------------
// One wave per node, single pass, unroll x8 (+x4 +scalar tail).
// esc gathered via record's e (edge-ordered esc4); h gathered via src.
// Lane owns dims {2*lane,2*lane+1}; head q = lane>>3.
// ---------------------------------------------------------------------------
__global__ __launch_bounds__(256) void node_aggregate(
    const uint2* __restrict__ noff, const int2* __restrict__ perm2,
    const __half* __restrict__ esc, const __half* __restrict__ h_fp,
    float* __restrict__ out)
{
    int lane = threadIdx.x & 63;
    int n = blockIdx.x * (blockDim.x >> 6) + (threadIdx.x >> 6);
    if (n >= NN) return;
    int q = lane >> 3;
    const unsigned int* hl = reinterpret_cast<const unsigned int*>(h_fp) + lane;
    const __half* el = esc + q;

    uint2 oc = noff[n];
    unsigned int s0 = oc.x, s1 = s0 + oc.y;
    float denom = 0.f, a0 = 0.f, a1 = 0.f;
    unsigned int i = s0;

    for (; i + 8 <= s1; i += 8) {
        int4 pa = *reinterpret_cast<const int4*>(&perm2[i]);
        int4 pb = *reinterpret_cast<const int4*>(&perm2[i + 2]);
        int4 pc = *reinterpret_cast<const int4*>(&perm2[i + 4]);
        int4 pd = *reinterpret_cast<const int4*>(&perm2[i + 6]);
        unsigned int u0 = hl[(size_t)pa.y * 64];
        unsigned int u1 = hl[(size_t)pa.w * 64];
        unsigned int u2 = hl[(size_t)pb.y * 64];
        unsigned int u3 = hl[(size_t)pb.w * 64];
        unsigned int u4 = hl[(size_t)pc.y * 64];
        unsigned int u5 = hl[(size_t)pc.w * 64];
        unsigned int u6 = hl[(size_t)pd.y * 64];
        unsigned int u7 = hl[(size_t)pd.w * 64];
        float e0 = __half2float(el[(size_t)pa.x * 8]);
        float e1 = __half2float(el[(size_t)pa.z * 8]);
        float e2 = __half2float(el[(size_t)pb.x * 8]);
        float e3 = __half2float(el[(size_t)pb.z * 8]);
        float e4 = __half2float(el[(size_t)pc.x * 8]);
        float e5 = __half2float(el[(size_t)pc.z * 8]);
        float e6 = __half2float(el[(size_t)pd.x * 8]);
        float e7 = __half2float(el[(size_t)pd.z * 8]);
        float2 h0 = __half22float2(*reinterpret_cast<const __half2*>(&u0));
        float2 h1 = __half22float2(*reinterpret_cast<const __half2*>(&u1));
        float2 h2 = __half22float2(*reinterpret_cast<const __half2*>(&u2));
        float2 h3 = __half22float2(*reinterpret_cast<const __half2*>(&u3));
        float2 h4 = __half22float2(*reinterpret_cast<const __half2*>(&u4));
        float2 h5 = __half22float2(*reinterpret_cast<const __half2*>(&u5));
        float2 h6 = __half22float2(*reinterpret_cast<const __half2*>(&u6));
        float2 h7 = __half22float2(*reinterpret_cast<const __half2*>(&u7));
        denom += ((e0 + e1) + (e2 + e3)) + ((e4 + e5) + (e6 + e7));
        a0 = fmaf(h0.x, e0, a0); a0 = fmaf(h1.x, e1, a0);
        a0 = fmaf(h2.x, e2, a0); a0 = fmaf(h3.x, e3, a0);
        a0 = fmaf(h4.x, e4, a0); a0 = fmaf(h5.x, e5, a0);
        a0 = fmaf(h6.x, e6, a0); a0 = fmaf(h7.x, e7, a0);
        a1 = fmaf(h0.y, e0, a1); a1 = fmaf(h1.y, e1, a1);
        a1 = fmaf(h2.y, e2, a1); a1 = fmaf(h3.y, e3, a1);
        a1 = fmaf(h4.y, e4, a1); a1 = fmaf(h5.y, e5, a1);
        a1 = fmaf(h6.y, e6, a1); a1 = fmaf(h7.y, e7, a1);
    }
    for (; i + 4 <= s1; i += 4) {
        int4 pa = *reinterpret_cast<const int4*>(&perm2[i]);
        int4 pb = *reinterpret_cast<const int4*>(&perm2[i + 2]);
        unsigned int u0 = hl[(size_t)pa.y * 64];
        unsigned int u1 = hl[(size_t)pa.w * 64];
        unsigned int u2 = hl[(size_t)pb.y * 64];
        unsigned int u3 = hl[(size_t)pb.w * 64];
        float e0 = __half2float(el[(size_t)pa.x * 8]);
        float e1 = __half2float(el[(size_t)pa.z * 8]);
        float e2 = __half2float(el[(size_t)pb.x * 8]);
        float e3 = __half2float(el[(size_t)pb.z * 8]);
        float2 h0 = __half22float2(*reinterpret_cast<const __half2*>(&u0));
        float2 h1 = __half22float2(*reinterpret_cast<const __half2*>(&u1));
        float2 h2 = __half22float2(*reinterpret_cast<const __half2*>(&u2));
        float2 h3 = __half22float2(*reinterpret_cast<const __half2*>(&u3));
        denom += (e0 + e1) + (e2 + e3);
        a0 = fmaf(h0.x, e0, a0); a0 = fmaf(h1.x, e1, a0);
        a0 = fmaf(h2.x, e2, a0); a0 = fmaf(h3.x, e3, a0);
        a1 = fmaf(h0.y, e0, a1); a1 = fmaf(h1.y, e1, a1);
        a1 = fmaf(h2.y, e2, a1); a1 = fmaf(h3.y, e3, a1);
    }
    for (; i < s1; ++i) {
        int2 p = perm2[i];
        unsigned int u = hl[(size_t)p.y * 64];
        float e = __half2float(el[(size_t)p.x * 8]);
        float2 hf = __half22float2(*reinterpret_cast<const __half2*>(&u));
        denom += e;
        a0 = fmaf(hf.x, e, a0);
        a1 = fmaf(hf.y, e, a1);
    }

    float w = 1.f / (denom + 1e-9f);
    a0 *= w; a1 *= w;
    a0 = a0 > 0.f ? a0 : expm1f(a0);
    a1 = a1 > 0.f ? a1 : expm1f(a1);
    reinterpret_cast<float2*>(out)[(size_t)n * 64 + lane] = make_float2(a0, a1);
}

extern "C" void kernel_launch(void* const* d_in, const int* in_sizes, int n_in,
                              void* d_out, int out_size, void* d_ws, size_t ws_size,
                              hipStream_t stream)
{
    const float* X    = (const float*)d_in[0];   // (N,128)
    const float* EF   = (const float*)d_in[1];   // (E,16)
    const float* Wn   = (const float*)d_in[2];   // (128,128)
    const float* We   = (const float*)d_in[3];   // (128,16)
    const float* attn = (const float*)d_in[4];   // (8,48)
    const int*   ei   = (const int*)d_in[5];     // (2,E)
    float* out = (float*)d_out;                  // (N,128)

    char* ws = (char*)d_ws;
    int2*   brec   = (int2*)ws;                                  // NB*BCAP int2 = 16.1MB
    u32x4*  esc4   = (u32x4*)(brec + (size_t)NB * BCAP);         // NE x 16B (edge order)
    __half* s_src16 = (__half*)(esc4 + NE);                      // NN*8 fp16 = 1.6MB
    __half* s_dst16 = s_src16 + (size_t)NN * 8;                  // NN*8 fp16 = 1.6MB
    float*  vbuf   = (float*)(s_dst16 + (size_t)NN * 8);         // 128
    unsigned int* bcursor = (unsigned int*)(vbuf + 128);         // 256
    uint2*  noff   = (uint2*)(bcursor + 256);                    // NN uint2
    __half* h_fp   = (__half*)(noff + NN);                       // NN*128 fp16

    hipMemsetAsync(bcursor, 0, 256 * sizeof(unsigned int), stream);

    prep_v_kernel<<<1, 128, 0, stream>>>(We, attn, vbuf);
    node_transform<<<(NN + NTB - 1) / NTB, 256, 0, stream>>>(X, Wn, attn, h_fp,
                                                             s_src16, s_dst16);
    edge_score_partition<<<(NE + EPB - 1) / EPB, 256, 0, stream>>>(
        ei, EF, vbuf, s_src16, s_dst16, bcursor, esc4, brec);
    bucket_sort<<<NB, 512, 0, stream>>>(bcursor, brec, noff);
    node_aggregate<<<(NN + 3) / 4, 256, 0, stream>>>(noff, brec,
                                                     (const __half*)esc4,
                                                     h_fp, out);
}